// Round 1
// baseline (208.725 us; speedup 1.0000x reference)
//
#include <hip/hip_runtime.h>
#include <hip/hip_bf16.h>
#include <stdint.h>

// Fused causal self-attention, B=2 T=2048 C=1024 H=16 D=64, bf16 MFMA compute.
// Pipeline: x->bf16 | w->bf16 transposed | fused QKV GEMM | V transpose |
//           flash attention | output projection GEMM (fp32 out).

typedef __attribute__((ext_vector_type(8))) short bf16x8;   // MFMA A/B frag (8 bf16)
typedef __attribute__((ext_vector_type(4))) float f32x4;    // MFMA C/D frag
typedef __attribute__((ext_vector_type(4))) short short4v;

#define MFMA16(a,b,c) __builtin_amdgcn_mfma_f32_16x16x32_bf16(a,b,c,0,0,0)

__device__ __forceinline__ unsigned short f2bfu(float f){
  union { __hip_bfloat16 h; unsigned short u; } cv;
  cv.h = __float2bfloat16(f);
  return cv.u;
}

__device__ __forceinline__ void async16(const void* g, void* s){
  __builtin_amdgcn_global_load_lds((const __attribute__((address_space(1))) void*)g,
                                   (__attribute__((address_space(3))) void*)s, 16, 0, 0);
}

// ---------------- prep kernels ----------------

__global__ __launch_bounds__(256) void convert_x_k(const float* __restrict__ x,
                                                   unsigned short* __restrict__ xb){
  const int i = blockIdx.x * 256 + threadIdx.x;
  const float4 v = ((const float4*)x)[i];
  short4v o;
  o.x = (short)f2bfu(v.x); o.y = (short)f2bfu(v.y);
  o.z = (short)f2bfu(v.z); o.w = (short)f2bfu(v.w);
  ((short4v*)xb)[i] = o;
}

// W[1024][1024] (in,out) fp32 -> Wt[1024][1024] (out,in) bf16
__global__ void transpose_w_k(const float* __restrict__ W, unsigned short* __restrict__ Wt){
  __shared__ float t[32][33];
  const int bx = blockIdx.x * 32, by = blockIdx.y * 32;
  const int tx = threadIdx.x, ty = threadIdx.y;
  #pragma unroll
  for (int i = 0; i < 32; i += 8)
    t[ty + i][tx] = W[(size_t)(by + ty + i) * 1024 + bx + tx];
  __syncthreads();
  #pragma unroll
  for (int i = 0; i < 32; i += 8)
    Wt[(size_t)(bx + ty + i) * 1024 + by + tx] = f2bfu(t[tx][ty + i]);
}

// V[32][2048][64] -> VT[32][64][2048]  (bf16 bits)
__global__ __launch_bounds__(256) void transpose_v_k(const unsigned short* __restrict__ V,
                                                     unsigned short* __restrict__ VT){
  __shared__ unsigned short tile[64][72];
  const int bh = blockIdx.y;
  const int t0 = blockIdx.x * 64;
  const int tid = threadIdx.x;
  const int r = tid >> 2;
  const int c = (tid & 3) * 16;
  const unsigned short* src = V + ((size_t)bh * 2048 + t0 + r) * 64 + c;
  *(uint4*)&tile[r][c]     = *(const uint4*)(src);
  *(uint4*)&tile[r][c + 8] = *(const uint4*)(src + 8);
  __syncthreads();
  const int d = tid >> 2;
  const int tt = (tid & 3) * 16;
  alignas(16) unsigned short tmp[16];
  #pragma unroll
  for (int j = 0; j < 16; j++) tmp[j] = tile[tt + j][d];
  unsigned short* dst = VT + ((size_t)bh * 64 + d) * 2048 + t0 + tt;
  *(uint4*)dst       = *(uint4*)&tmp[0];
  *(uint4*)(dst + 8) = *(uint4*)&tmp[8];
}

// ---------------- GEMM: C[M][N] = A[M][1024] * Bt[N][1024]^T ----------------
// MODE 0: fused QKV (N=3072), writes Q (scaled 0.125) / K / V in [B,H,T,D] bf16
// MODE 1: projection (N=1024), writes fp32 + bias to out
template<int MODE>
__global__ __launch_bounds__(256)
void gemm_bt(const unsigned short* __restrict__ A, const unsigned short* __restrict__ Bt,
             const float* __restrict__ b0, const float* __restrict__ b1, const float* __restrict__ b2,
             unsigned short* __restrict__ Qo, unsigned short* __restrict__ Ko,
             unsigned short* __restrict__ Vo, float* __restrict__ Fo, int N)
{
  constexpr int K = 1024;
  __shared__ unsigned short As[128 * 32];
  __shared__ unsigned short Bs[128 * 32];
  const int tid = threadIdx.x;
  const int lane = tid & 63;
  const int w = tid >> 6;
  const int l15 = lane & 15, lhi = lane >> 4;
  const int row0 = blockIdx.y * 128;
  const int col0 = blockIdx.x * 128;
  const int wr = (w >> 1) * 64;
  const int wc = (w & 1) * 64;

  f32x4 acc[4][4];
  #pragma unroll
  for (int i = 0; i < 4; i++)
    #pragma unroll
    for (int j = 0; j < 4; j++) acc[i][j] = 0.0f;

  const int srow = lane >> 2;          // 0..15
  const int scol = (lane & 3) * 8;     // elem offset
  const unsigned short* Ab = A  + (size_t)(row0 + w * 32 + srow) * K + scol;
  const unsigned short* Bb = Bt + (size_t)(col0 + w * 32 + srow) * K + scol;
  unsigned short* AsW = As + (w * 32) * 32;   // wave-uniform LDS base
  unsigned short* BsW = Bs + (w * 32) * 32;

  for (int k0 = 0; k0 < K; k0 += 32) {
    __syncthreads();
    async16(Ab + k0,          AsW);
    async16(Ab + k0 + 16 * K, AsW + 16 * 32);
    async16(Bb + k0,          BsW);
    async16(Bb + k0 + 16 * K, BsW + 16 * 32);
    __syncthreads();
    bf16x8 af[4], bfv[4];
    #pragma unroll
    for (int i = 0; i < 4; i++) {
      af[i]  = *(const bf16x8*)&As[(wr + i * 16 + l15) * 32 + lhi * 8];
      bfv[i] = *(const bf16x8*)&Bs[(wc + i * 16 + l15) * 32 + lhi * 8];
    }
    #pragma unroll
    for (int i = 0; i < 4; i++)
      #pragma unroll
      for (int j = 0; j < 4; j++)
        acc[i][j] = MFMA16(af[i], bfv[j], acc[i][j]);
  }

  #pragma unroll
  for (int j = 0; j < 4; j++) {
    const int n = col0 + wc + j * 16 + l15;
    if constexpr (MODE == 0) {
      const int which = n >> 10;
      const int cn = n & 1023;
      const float bias = (which == 0 ? b0[cn] : which == 1 ? b1[cn] : b2[cn]);
      unsigned short* dst = (which == 0 ? Qo : which == 1 ? Ko : Vo);
      const float sc = (which == 0 ? 0.125f : 1.0f);
      const int h = cn >> 6, d = cn & 63;
      #pragma unroll
      for (int i = 0; i < 4; i++)
        #pragma unroll
        for (int r = 0; r < 4; r++) {
          const int m = row0 + wr + i * 16 + lhi * 4 + r;
          const int b_ = m >> 11, t = m & 2047;
          dst[(((size_t)(b_ * 16 + h) * 2048 + t) * 64) + d] =
              f2bfu((acc[i][j][r] + bias) * sc);
        }
    } else {
      const float bias = b0[n];
      #pragma unroll
      for (int i = 0; i < 4; i++)
        #pragma unroll
        for (int r = 0; r < 4; r++) {
          const int m = row0 + wr + i * 16 + lhi * 4 + r;
          Fo[(size_t)m * N + n] = acc[i][j][r] + bias;
        }
    }
  }
}

// ---------------- flash attention ----------------
// grid (T/64, B*H); 4 waves/block, wave w owns 16 q rows. KV tiles of 64.
__global__ __launch_bounds__(256)
void attn_k(const unsigned short* __restrict__ Q, const unsigned short* __restrict__ Kg,
            const unsigned short* __restrict__ VT, unsigned short* __restrict__ O)
{
  __shared__ unsigned short Ks[64 * 64];
  __shared__ unsigned short Vs[64 * 64];
  __shared__ unsigned short Ps[4][16 * 64];
  const int bh = blockIdx.y;
  const int qt = blockIdx.x;
  const int b_ = bh >> 4, h = bh & 15;
  const int tid = threadIdx.x, lane = tid & 63, w = tid >> 6;
  const int l15 = lane & 15, lhi = lane >> 4;
  const int q0 = qt * 64 + w * 16;

  const unsigned short* Qp = Q + ((size_t)bh * 2048 + q0 + l15) * 64 + lhi * 8;
  const bf16x8 qf0 = *(const bf16x8*)(Qp);
  const bf16x8 qf1 = *(const bf16x8*)(Qp + 32);

  f32x4 o[4];
  #pragma unroll
  for (int nf = 0; nf < 4; nf++) o[nf] = 0.0f;
  float mrun[4], lrun[4];
  #pragma unroll
  for (int r = 0; r < 4; r++) { mrun[r] = -1e30f; lrun[r] = 0.0f; }

  const int srow = tid >> 3;        // 0..31
  const int sce  = (tid & 7) * 8;   // elem col in 64-elem row

  const int nt = qt + 1;
  for (int j = 0; j < nt; ++j) {
    const int kv0 = j * 64;
    __syncthreads();
    #pragma unroll
    for (int it = 0; it < 2; ++it) {
      const int row = it * 32 + srow;
      const uint4 kd = *(const uint4*)(Kg + ((size_t)bh * 2048 + kv0 + row) * 64 + sce);
      const uint4 vd = *(const uint4*)(VT + ((size_t)bh * 64 + row) * 2048 + kv0 + sce);
      int byte = row * 128 + sce * 2;
      byte ^= (row & 7) << 4;                 // bank-conflict swizzle
      *(uint4*)((char*)Ks + byte) = kd;
      *(uint4*)((char*)Vs + byte) = vd;
    }
    __syncthreads();

    // S = Q K^T  (D[q][kv]: col=kv=l15, row=q=lhi*4+r)
    f32x4 s[4];
    #pragma unroll
    for (int nf = 0; nf < 4; ++nf) {
      s[nf] = 0.0f;
      const int rk = nf * 16 + l15;
      const int swz = (rk & 7) << 4;
      const bf16x8 kf0 = *(const bf16x8*)((char*)Ks + ((rk * 128 + lhi * 16) ^ swz));
      const bf16x8 kf1 = *(const bf16x8*)((char*)Ks + ((rk * 128 + 64 + lhi * 16) ^ swz));
      s[nf] = MFMA16(qf0, kf0, s[nf]);
      s[nf] = MFMA16(qf1, kf1, s[nf]);
    }

    if (j == qt) {      // causal mask (only last tile straddles the diagonal)
      #pragma unroll
      for (int nf = 0; nf < 4; ++nf) {
        const int kv = kv0 + nf * 16 + l15;
        #pragma unroll
        for (int r = 0; r < 4; r++) {
          const int q = q0 + lhi * 4 + r;
          if (kv > q) s[nf][r] = -1e30f;
        }
      }
    }

    // online softmax: row reduce over 16 lanes (kv cols) x 4 frags
    float pm[4];
    #pragma unroll
    for (int r = 0; r < 4; r++)
      pm[r] = fmaxf(fmaxf(s[0][r], s[1][r]), fmaxf(s[2][r], s[3][r]));
    #pragma unroll
    for (int off = 1; off < 16; off <<= 1)
      #pragma unroll
      for (int r = 0; r < 4; r++)
        pm[r] = fmaxf(pm[r], __shfl_xor(pm[r], off, 64));

    float scalef[4], rsum[4];
    #pragma unroll
    for (int r = 0; r < 4; r++) {
      const float mnew = fmaxf(mrun[r], pm[r]);
      scalef[r] = __expf(mrun[r] - mnew);
      mrun[r] = mnew;
      rsum[r] = 0.0f;
    }
    unsigned short pb[4][4];
    #pragma unroll
    for (int nf = 0; nf < 4; nf++)
      #pragma unroll
      for (int r = 0; r < 4; r++) {
        const float p = __expf(s[nf][r] - mrun[r]);
        rsum[r] += p;
        pb[nf][r] = f2bfu(p);
      }
    #pragma unroll
    for (int off = 1; off < 16; off <<= 1)
      #pragma unroll
      for (int r = 0; r < 4; r++)
        rsum[r] += __shfl_xor(rsum[r], off, 64);
    #pragma unroll
    for (int r = 0; r < 4; r++)
      lrun[r] = lrun[r] * scalef[r] + rsum[r];
    #pragma unroll
    for (int nf = 0; nf < 4; nf++)
      #pragma unroll
      for (int r = 0; r < 4; r++)
        o[nf][r] *= scalef[r];

    // P via per-wave swizzled LDS to fix C/D -> A-operand layout
    unsigned short* Pw = &Ps[w][0];
    #pragma unroll
    for (int nf = 0; nf < 4; nf++)
      #pragma unroll
      for (int r = 0; r < 4; r++) {
        const int row = lhi * 4 + r;
        const int byte = (row * 128 + (nf * 16 + l15) * 2) ^ ((row & 7) << 4);
        *(unsigned short*)((char*)Pw + byte) = pb[nf][r];
      }
    const int rp = l15;
    const int swp = (rp & 7) << 4;
    const bf16x8 pf0 = *(const bf16x8*)((char*)Pw + ((rp * 128 + lhi * 16) ^ swp));
    const bf16x8 pf1 = *(const bf16x8*)((char*)Pw + ((rp * 128 + 64 + lhi * 16) ^ swp));

    // O += P V   (B operand from VT rows: n=d, k=kv)
    #pragma unroll
    for (int nf = 0; nf < 4; nf++) {
      const int rv = nf * 16 + l15;
      const int swv = (rv & 7) << 4;
      const bf16x8 vf0 = *(const bf16x8*)((char*)Vs + ((rv * 128 + lhi * 16) ^ swv));
      const bf16x8 vf1 = *(const bf16x8*)((char*)Vs + ((rv * 128 + 64 + lhi * 16) ^ swv));
      o[nf] = MFMA16(pf0, vf0, o[nf]);
      o[nf] = MFMA16(pf1, vf1, o[nf]);
    }
  }

  float inv[4];
  #pragma unroll
  for (int r = 0; r < 4; r++) inv[r] = 1.0f / lrun[r];
  #pragma unroll
  for (int nf = 0; nf < 4; nf++)
    #pragma unroll
    for (int r = 0; r < 4; r++) {
      const int t = q0 + lhi * 4 + r;
      const int c = h * 64 + nf * 16 + l15;
      O[((size_t)b_ * 2048 + t) * 1024 + c] = f2bfu(o[nf][r] * inv[r]);
    }
}

// ---------------- launch ----------------

extern "C" void kernel_launch(void* const* d_in, const int* in_sizes, int n_in,
                              void* d_out, int out_size, void* d_ws, size_t ws_size,
                              hipStream_t stream) {
  const float* x  = (const float*)d_in[0];
  const float* wq = (const float*)d_in[1];
  const float* bq = (const float*)d_in[2];
  const float* wk = (const float*)d_in[3];
  const float* bk = (const float*)d_in[4];
  const float* wv = (const float*)d_in[5];
  const float* bv = (const float*)d_in[6];
  const float* wp = (const float*)d_in[7];
  const float* bp = (const float*)d_in[8];
  float* out = (float*)d_out;

  char* ws = (char*)d_ws;
  const size_t MB = 1024 * 1024;
  unsigned short* xb    = (unsigned short*)(ws);             // 8MB  [4096][1024]
  unsigned short* wqkvT = (unsigned short*)(ws + 8  * MB);   // 6MB  [3072][1024]
  unsigned short* wpT   = (unsigned short*)(ws + 14 * MB);   // 2MB  [1024][1024]
  unsigned short* Qb    = (unsigned short*)(ws + 16 * MB);   // 8MB  [32][2048][64]
  unsigned short* Kb    = (unsigned short*)(ws + 24 * MB);   // 8MB
  unsigned short* Vb    = (unsigned short*)(ws + 32 * MB);   // 8MB
  unsigned short* VTb   = (unsigned short*)(ws);             // alias xb (dead after QKV GEMM)
  unsigned short* Ob    = (unsigned short*)(ws + 32 * MB);   // alias Vb (dead after V transpose)

  convert_x_k<<<dim3(4096), dim3(256), 0, stream>>>(x, xb);
  transpose_w_k<<<dim3(32, 32), dim3(32, 8), 0, stream>>>(wq, wqkvT);
  transpose_w_k<<<dim3(32, 32), dim3(32, 8), 0, stream>>>(wk, wqkvT + 1024 * 1024);
  transpose_w_k<<<dim3(32, 32), dim3(32, 8), 0, stream>>>(wv, wqkvT + 2 * 1024 * 1024);
  transpose_w_k<<<dim3(32, 32), dim3(32, 8), 0, stream>>>(wp, wpT);

  gemm_bt<0><<<dim3(24, 32), dim3(256), 0, stream>>>(xb, wqkvT, bq, bk, bv,
                                                     Qb, Kb, Vb, nullptr, 3072);
  transpose_v_k<<<dim3(32, 32), dim3(256), 0, stream>>>(Vb, VTb);
  attn_k<<<dim3(32, 32), dim3(256), 0, stream>>>(Qb, Kb, VTb, Ob);
  gemm_bt<1><<<dim3(8, 32), dim3(256), 0, stream>>>(Ob, wpT, bp, nullptr, nullptr,
                                                    nullptr, nullptr, nullptr, out, 1024);
}

// Round 2
// 166.058 us; speedup vs baseline: 1.2569x; 1.2569x over previous
//
#include <hip/hip_runtime.h>
#include <hip/hip_bf16.h>
#include <stdint.h>

// Fused causal self-attention, B=2 T=2048 C=1024 H=16 D=64, bf16 MFMA compute.
// Pipeline: x->bf16 | w->bf16 transposed | fused QKV GEMM | V transpose |
//           flash attention (paired q-tiles, dbuf KV prefetch) | out projection.

typedef __attribute__((ext_vector_type(8))) short bf16x8;   // MFMA A/B frag (8 bf16)
typedef __attribute__((ext_vector_type(4))) float f32x4;    // MFMA C/D frag
typedef __attribute__((ext_vector_type(4))) short short4v;

#define MFMA16(a,b,c) __builtin_amdgcn_mfma_f32_16x16x32_bf16(a,b,c,0,0,0)

__device__ __forceinline__ unsigned short f2bfu(float f){
  union { __hip_bfloat16 h; unsigned short u; } cv;
  cv.h = __float2bfloat16(f);
  return cv.u;
}

__device__ __forceinline__ void async16(const void* g, void* s){
  __builtin_amdgcn_global_load_lds((const __attribute__((address_space(1))) void*)g,
                                   (__attribute__((address_space(3))) void*)s, 16, 0, 0);
}

// ---------------- prep kernels ----------------

__global__ __launch_bounds__(256) void convert_x_k(const float* __restrict__ x,
                                                   unsigned short* __restrict__ xb){
  const int i = blockIdx.x * 256 + threadIdx.x;
  const float4 v = ((const float4*)x)[i];
  short4v o;
  o.x = (short)f2bfu(v.x); o.y = (short)f2bfu(v.y);
  o.z = (short)f2bfu(v.z); o.w = (short)f2bfu(v.w);
  ((short4v*)xb)[i] = o;
}

// W[1024][1024] (in,out) fp32 -> Wt[1024][1024] (out,in) bf16
__global__ void transpose_w_k(const float* __restrict__ W, unsigned short* __restrict__ Wt){
  __shared__ float t[32][33];
  const int bx = blockIdx.x * 32, by = blockIdx.y * 32;
  const int tx = threadIdx.x, ty = threadIdx.y;
  #pragma unroll
  for (int i = 0; i < 32; i += 8)
    t[ty + i][tx] = W[(size_t)(by + ty + i) * 1024 + bx + tx];
  __syncthreads();
  #pragma unroll
  for (int i = 0; i < 32; i += 8)
    Wt[(size_t)(bx + ty + i) * 1024 + by + tx] = f2bfu(t[tx][ty + i]);
}

// V[32][2048][64] -> VT[32][64][2048]  (bf16 bits)
__global__ __launch_bounds__(256) void transpose_v_k(const unsigned short* __restrict__ V,
                                                     unsigned short* __restrict__ VT){
  __shared__ unsigned short tile[64][72];
  const int bh = blockIdx.y;
  const int t0 = blockIdx.x * 64;
  const int tid = threadIdx.x;
  const int r = tid >> 2;
  const int c = (tid & 3) * 16;
  const unsigned short* src = V + ((size_t)bh * 2048 + t0 + r) * 64 + c;
  *(uint4*)&tile[r][c]     = *(const uint4*)(src);
  *(uint4*)&tile[r][c + 8] = *(const uint4*)(src + 8);
  __syncthreads();
  const int d = tid >> 2;
  const int tt = (tid & 3) * 16;
  alignas(16) unsigned short tmp[16];
  #pragma unroll
  for (int j = 0; j < 16; j++) tmp[j] = tile[tt + j][d];
  unsigned short* dst = VT + ((size_t)bh * 64 + d) * 2048 + t0 + tt;
  *(uint4*)dst       = *(uint4*)&tmp[0];
  *(uint4*)(dst + 8) = *(uint4*)&tmp[8];
}

// ---------------- GEMM: C[M][N] = A[M][1024] * Bt[N][1024]^T ----------------
// MODE 0: fused QKV (N=3072), writes Q (scaled 0.125*log2e) / K / V in [B,H,T,D] bf16
// MODE 1: projection (N=1024), writes fp32 + bias to out
template<int MODE>
__global__ __launch_bounds__(256)
void gemm_bt(const unsigned short* __restrict__ A, const unsigned short* __restrict__ Bt,
             const float* __restrict__ b0, const float* __restrict__ b1, const float* __restrict__ b2,
             unsigned short* __restrict__ Qo, unsigned short* __restrict__ Ko,
             unsigned short* __restrict__ Vo, float* __restrict__ Fo, int N)
{
  constexpr int K = 1024;
  __shared__ unsigned short As[128 * 32];
  __shared__ unsigned short Bs[128 * 32];
  const int tid = threadIdx.x;
  const int lane = tid & 63;
  const int w = tid >> 6;
  const int l15 = lane & 15, lhi = lane >> 4;
  const int row0 = blockIdx.y * 128;
  const int col0 = blockIdx.x * 128;
  const int wr = (w >> 1) * 64;
  const int wc = (w & 1) * 64;

  f32x4 acc[4][4];
  #pragma unroll
  for (int i = 0; i < 4; i++)
    #pragma unroll
    for (int j = 0; j < 4; j++) acc[i][j] = 0.0f;

  const int srow = lane >> 2;          // 0..15
  const int scol = (lane & 3) * 8;     // elem offset
  const unsigned short* Ab = A  + (size_t)(row0 + w * 32 + srow) * K + scol;
  const unsigned short* Bb = Bt + (size_t)(col0 + w * 32 + srow) * K + scol;
  unsigned short* AsW = As + (w * 32) * 32;   // wave-uniform LDS base
  unsigned short* BsW = Bs + (w * 32) * 32;

  for (int k0 = 0; k0 < K; k0 += 32) {
    __syncthreads();
    async16(Ab + k0,          AsW);
    async16(Ab + k0 + 16 * K, AsW + 16 * 32);
    async16(Bb + k0,          BsW);
    async16(Bb + k0 + 16 * K, BsW + 16 * 32);
    __syncthreads();
    bf16x8 af[4], bfv[4];
    #pragma unroll
    for (int i = 0; i < 4; i++) {
      af[i]  = *(const bf16x8*)&As[(wr + i * 16 + l15) * 32 + lhi * 8];
      bfv[i] = *(const bf16x8*)&Bs[(wc + i * 16 + l15) * 32 + lhi * 8];
    }
    #pragma unroll
    for (int i = 0; i < 4; i++)
      #pragma unroll
      for (int j = 0; j < 4; j++)
        acc[i][j] = MFMA16(af[i], bfv[j], acc[i][j]);
  }

  #pragma unroll
  for (int j = 0; j < 4; j++) {
    const int n = col0 + wc + j * 16 + l15;
    if constexpr (MODE == 0) {
      const int which = n >> 10;
      const int cn = n & 1023;
      const float bias = (which == 0 ? b0[cn] : which == 1 ? b1[cn] : b2[cn]);
      unsigned short* dst = (which == 0 ? Qo : which == 1 ? Ko : Vo);
      // Q carries 1/sqrt(D) * log2(e) so attention can use exp2 directly
      const float sc = (which == 0 ? 0.125f * 1.44269504f : 1.0f);
      const int h = cn >> 6, d = cn & 63;
      #pragma unroll
      for (int i = 0; i < 4; i++)
        #pragma unroll
        for (int r = 0; r < 4; r++) {
          const int m = row0 + wr + i * 16 + lhi * 4 + r;
          const int b_ = m >> 11, t = m & 2047;
          dst[(((size_t)(b_ * 16 + h) * 2048 + t) * 64) + d] =
              f2bfu((acc[i][j][r] + bias) * sc);
        }
    } else {
      const float bias = b0[n];
      #pragma unroll
      for (int i = 0; i < 4; i++)
        #pragma unroll
        for (int r = 0; r < 4; r++) {
          const int m = row0 + wr + i * 16 + lhi * 4 + r;
          Fo[(size_t)m * N + n] = acc[i][j][r] + bias;
        }
    }
  }
}

// ---------------- flash attention ----------------
// grid (16, B*H): block x handles q-tiles x (light) and 31-x (heavy) -> uniform
// 33 tile-iters. 4 waves, wave owns 16 q rows of each set. KV tiles of 64,
// double-buffered LDS, prefetched via global_load_lds with pre-swizzled source.

__device__ __forceinline__ void attn_tile(
    const unsigned short* __restrict__ Ksb, const unsigned short* __restrict__ Vsb,
    unsigned short* __restrict__ Pw,
    bf16x8 qf0, bf16x8 qf1,
    f32x4 (&o)[4], float (&mrun)[4], float (&lrun)[4],
    int l15, int lhi, int q0, int kv0, bool mask)
{
  // S = Q K^T  (D[q][kv]: col=kv=l15, row=q=lhi*4+r); S already in log2 units
  f32x4 s[4];
  __builtin_amdgcn_s_setprio(1);
  #pragma unroll
  for (int nf = 0; nf < 4; ++nf) {
    s[nf] = 0.0f;
    const int rk = nf * 16 + l15;
    const int swz = (rk & 7) << 4;
    const bf16x8 kf0 = *(const bf16x8*)((const char*)Ksb + ((rk * 128 + lhi * 16) ^ swz));
    const bf16x8 kf1 = *(const bf16x8*)((const char*)Ksb + ((rk * 128 + 64 + lhi * 16) ^ swz));
    s[nf] = MFMA16(qf0, kf0, s[nf]);
    s[nf] = MFMA16(qf1, kf1, s[nf]);
  }
  __builtin_amdgcn_s_setprio(0);

  if (mask) {
    #pragma unroll
    for (int nf = 0; nf < 4; ++nf) {
      const int kv = kv0 + nf * 16 + l15;
      #pragma unroll
      for (int r = 0; r < 4; r++) {
        const int q = q0 + lhi * 4 + r;
        if (kv > q) s[nf][r] = -1e30f;
      }
    }
  }

  // online softmax (log2 domain), 16-lane reduce, deferred rescale (thr 8)
  float pm[4];
  #pragma unroll
  for (int r = 0; r < 4; r++)
    pm[r] = fmaxf(fmaxf(s[0][r], s[1][r]), fmaxf(s[2][r], s[3][r]));
  #pragma unroll
  for (int off = 1; off < 16; off <<= 1)
    #pragma unroll
    for (int r = 0; r < 4; r++)
      pm[r] = fmaxf(pm[r], __shfl_xor(pm[r], off, 64));

  bool big = false;
  #pragma unroll
  for (int r = 0; r < 4; r++) big = big || (pm[r] > mrun[r] + 8.0f);
  if (__any(big)) {
    #pragma unroll
    for (int r = 0; r < 4; r++) {
      const float mnew = fmaxf(mrun[r], pm[r]);
      const float sc = exp2f(mrun[r] - mnew);
      mrun[r] = mnew;
      lrun[r] *= sc;
      #pragma unroll
      for (int nf = 0; nf < 4; nf++) o[nf][r] *= sc;
    }
  }

  float rsum[4] = {0.f, 0.f, 0.f, 0.f};
  #pragma unroll
  for (int nf = 0; nf < 4; nf++)
    #pragma unroll
    for (int r = 0; r < 4; r++) {
      const float p = exp2f(s[nf][r] - mrun[r]);
      rsum[r] += p;
      const int row = lhi * 4 + r;
      const int byte = (row * 128 + (nf * 16 + l15) * 2) ^ ((row & 7) << 4);
      *(unsigned short*)((char*)Pw + byte) = f2bfu(p);
    }
  #pragma unroll
  for (int off = 1; off < 16; off <<= 1)
    #pragma unroll
    for (int r = 0; r < 4; r++)
      rsum[r] += __shfl_xor(rsum[r], off, 64);
  #pragma unroll
  for (int r = 0; r < 4; r++) lrun[r] += rsum[r];

  // P frags back from per-wave LDS
  const int rp = l15;
  const int swp = (rp & 7) << 4;
  const bf16x8 pf0 = *(const bf16x8*)((const char*)Pw + ((rp * 128 + lhi * 16) ^ swp));
  const bf16x8 pf1 = *(const bf16x8*)((const char*)Pw + ((rp * 128 + 64 + lhi * 16) ^ swp));

  // O += P V   (B operand from Vs rows: n=d, k=kv)
  __builtin_amdgcn_s_setprio(1);
  #pragma unroll
  for (int nf = 0; nf < 4; nf++) {
    const int rv = nf * 16 + l15;
    const int swv = (rv & 7) << 4;
    const bf16x8 vf0 = *(const bf16x8*)((const char*)Vsb + ((rv * 128 + lhi * 16) ^ swv));
    const bf16x8 vf1 = *(const bf16x8*)((const char*)Vsb + ((rv * 128 + 64 + lhi * 16) ^ swv));
    o[nf] = MFMA16(pf0, vf0, o[nf]);
    o[nf] = MFMA16(pf1, vf1, o[nf]);
  }
  __builtin_amdgcn_s_setprio(0);
}

__global__ __launch_bounds__(256)
void attn_k(const unsigned short* __restrict__ Q, const unsigned short* __restrict__ Kg,
            const unsigned short* __restrict__ VT, unsigned short* __restrict__ O)
{
  __shared__ unsigned short Ks[2][64 * 64];
  __shared__ unsigned short Vs[2][64 * 64];
  __shared__ unsigned short Ps[4][16 * 64];
  const int bh = blockIdx.y;
  const int x = blockIdx.x;              // pair id 0..15
  const int tA = x, tB = 31 - x;         // q-tile indices (A light, B heavy)
  const int b_ = bh >> 4, h = bh & 15;
  const int tid = threadIdx.x, lane = tid & 63, w = tid >> 6;
  const int l15 = lane & 15, lhi = lane >> 4;
  const int q0A = tA * 64 + w * 16;
  const int q0B = tB * 64 + w * 16;

  const unsigned short* QpA = Q + ((size_t)bh * 2048 + q0A + l15) * 64 + lhi * 8;
  const unsigned short* QpB = Q + ((size_t)bh * 2048 + q0B + l15) * 64 + lhi * 8;
  const bf16x8 qfA0 = *(const bf16x8*)(QpA);
  const bf16x8 qfA1 = *(const bf16x8*)(QpA + 32);
  const bf16x8 qfB0 = *(const bf16x8*)(QpB);
  const bf16x8 qfB1 = *(const bf16x8*)(QpB + 32);

  f32x4 oA[4], oB[4];
  float mrunA[4], lrunA[4], mrunB[4], lrunB[4];
  #pragma unroll
  for (int nf = 0; nf < 4; nf++) { oA[nf] = 0.0f; oB[nf] = 0.0f; }
  #pragma unroll
  for (int r = 0; r < 4; r++) {
    mrunA[r] = -1e30f; lrunA[r] = 0.0f;
    mrunB[r] = -1e30f; lrunB[r] = 0.0f;
  }

  // staging: linear LDS dest (tid*16B), pre-swizzled per-lane global source.
  // LDS byte b holds (row=b>>7, colbyte=(b&127)^((row&7)<<4)).
  const int srow = w * 8 + (lane >> 3);                 // + it*32
  const int cole = (((lane & 7) ^ (lane >> 3)) << 3);   // element offset (16B blk)
  const unsigned short* Ksrc = Kg + (size_t)bh * (2048 * 64) + (size_t)srow * 64 + cole;
  const unsigned short* Vsrc = VT + (size_t)bh * (64 * 2048) + (size_t)srow * 2048 + cole;

  auto stage = [&](int kv0, int buf) {
    unsigned short* kb = &Ks[buf][w * 512];   // w*1024 bytes, wave-uniform
    unsigned short* vb = &Vs[buf][w * 512];
    #pragma unroll
    for (int it = 0; it < 2; ++it) {
      async16(Ksrc + (size_t)(kv0 + it * 32) * 64, kb + it * 2048);
      async16(Vsrc + (size_t)(it * 32) * 2048 + kv0, vb + it * 2048);
    }
  };

  stage(0, 0);
  __syncthreads();     // drains vmcnt before first compute

  const int ntB = tB + 1;
  int cur = 0;
  for (int j = 0; j < ntB; ++j) {
    if (j + 1 < ntB) stage((j + 1) * 64, cur ^ 1);   // prefetch next tile
    const int kv0 = j * 64;
    attn_tile(&Ks[cur][0], &Vs[cur][0], &Ps[w][0], qfB0, qfB1,
              oB, mrunB, lrunB, l15, lhi, q0B, kv0, j == tB);
    if (j <= tA)
      attn_tile(&Ks[cur][0], &Vs[cur][0], &Ps[w][0], qfA0, qfA1,
                oA, mrunA, lrunA, l15, lhi, q0A, kv0, j == tA);
    __syncthreads();   // vmcnt(0)+barrier: prefetch landed, buffers free
    cur ^= 1;
  }

  float invA[4], invB[4];
  #pragma unroll
  for (int r = 0; r < 4; r++) { invA[r] = 1.0f / lrunA[r]; invB[r] = 1.0f / lrunB[r]; }
  #pragma unroll
  for (int nf = 0; nf < 4; nf++)
    #pragma unroll
    for (int r = 0; r < 4; r++) {
      const int c = h * 64 + nf * 16 + l15;
      const int tAi = q0A + lhi * 4 + r;
      const int tBi = q0B + lhi * 4 + r;
      O[((size_t)b_ * 2048 + tAi) * 1024 + c] = f2bfu(oA[nf][r] * invA[r]);
      O[((size_t)b_ * 2048 + tBi) * 1024 + c] = f2bfu(oB[nf][r] * invB[r]);
    }
}

// ---------------- launch ----------------

extern "C" void kernel_launch(void* const* d_in, const int* in_sizes, int n_in,
                              void* d_out, int out_size, void* d_ws, size_t ws_size,
                              hipStream_t stream) {
  const float* x  = (const float*)d_in[0];
  const float* wq = (const float*)d_in[1];
  const float* bq = (const float*)d_in[2];
  const float* wk = (const float*)d_in[3];
  const float* bk = (const float*)d_in[4];
  const float* wv = (const float*)d_in[5];
  const float* bv = (const float*)d_in[6];
  const float* wp = (const float*)d_in[7];
  const float* bp = (const float*)d_in[8];
  float* out = (float*)d_out;

  char* ws = (char*)d_ws;
  const size_t MB = 1024 * 1024;
  unsigned short* xb    = (unsigned short*)(ws);             // 8MB  [4096][1024]
  unsigned short* wqkvT = (unsigned short*)(ws + 8  * MB);   // 6MB  [3072][1024]
  unsigned short* wpT   = (unsigned short*)(ws + 14 * MB);   // 2MB  [1024][1024]
  unsigned short* Qb    = (unsigned short*)(ws + 16 * MB);   // 8MB  [32][2048][64]
  unsigned short* Kb    = (unsigned short*)(ws + 24 * MB);   // 8MB
  unsigned short* Vb    = (unsigned short*)(ws + 32 * MB);   // 8MB
  unsigned short* VTb   = (unsigned short*)(ws);             // alias xb (dead after QKV GEMM)
  unsigned short* Ob    = (unsigned short*)(ws + 32 * MB);   // alias Vb (dead after V transpose)

  convert_x_k<<<dim3(4096), dim3(256), 0, stream>>>(x, xb);
  transpose_w_k<<<dim3(32, 32), dim3(32, 8), 0, stream>>>(wq, wqkvT);
  transpose_w_k<<<dim3(32, 32), dim3(32, 8), 0, stream>>>(wk, wqkvT + 1024 * 1024);
  transpose_w_k<<<dim3(32, 32), dim3(32, 8), 0, stream>>>(wv, wqkvT + 2 * 1024 * 1024);
  transpose_w_k<<<dim3(32, 32), dim3(32, 8), 0, stream>>>(wp, wpT);

  gemm_bt<0><<<dim3(24, 32), dim3(256), 0, stream>>>(xb, wqkvT, bq, bk, bv,
                                                     Qb, Kb, Vb, nullptr, 3072);
  transpose_v_k<<<dim3(32, 32), dim3(256), 0, stream>>>(Vb, VTb);
  attn_k<<<dim3(16, 32), dim3(256), 0, stream>>>(Qb, Kb, VTb, Ob);
  gemm_bt<1><<<dim3(8, 32), dim3(256), 0, stream>>>(Ob, wpT, bp, nullptr, nullptr,
                                                    nullptr, nullptr, nullptr, out, 1024);
}